// Round 4
// baseline (1898.656 us; speedup 1.0000x reference)
//
#include <hip/hip_runtime.h>
#include <hip/hip_cooperative_groups.h>

namespace cg = cooperative_groups;

#define K_ITER   30
#define MU       0.01f
#define EPS      1e-6f
#define MAX_LS   25
#define FULLMASK 0x01FFFFFFu
#define MM       128
#define NN       256
#define NPROB    512

// ---- d_ws layout ----
// [0, 128)   bytes : gmask (unsigned[32])
// [256, ...) bytes : fallback-path state arrays (floats)
#define OX   ((size_t)0)                    // x        [NPROB*NN]
#define OG   ((size_t)(NPROB*NN))           // grad     [NPROB*NN]
#define OAX  ((size_t)(2*NPROB*NN))         // Ax       [NPROB*MM]
#define OAG  (OAX + (size_t)(NPROB*MM))     // Ag       [NPROB*MM]
#define OR_  (OAG + (size_t)(NPROB*MM))     // rownorm  [NPROB*MM]

#define BFLY_ADD(v) do { \
    v += __shfl_xor(v, 1);  v += __shfl_xor(v, 2);  v += __shfl_xor(v, 4); \
    v += __shfl_xor(v, 8);  v += __shfl_xor(v, 16); v += __shfl_xor(v, 32); } while (0)

__global__ void lbp_gmask_init(unsigned* __restrict__ gmask) {
    if (threadIdx.x < K_ITER) gmask[threadIdx.x] = FULLMASK;
}

// ================= persistent cooperative kernel (primary path) ===========
// 512 blocks x 256 threads (4 waves). Wave w owns rows 32w..32w+31; lane l
// owns cols 4l..4l+3.  A lives in 32 float4 = 128 VGPRs per thread.
__global__ __launch_bounds__(256, 2)
void lbp_persist(const float* __restrict__ xraw_g,
                 const float* __restrict__ A_g,
                 const float* __restrict__ b_g,
                 const float* __restrict__ lower_g,
                 float* __restrict__ out_g,
                 unsigned* __restrict__ gmask)
{
    const int p    = blockIdx.x;
    const int t    = threadIdx.x;      // 0..255 (== column n)
    const int lane = t & 63;
    const int wave = t >> 6;           // 0..3

    const float* A = A_g + (size_t)p * MM * NN;

    __shared__ __align__(16) float s_x[NN], s_grad[NN], s_xraw[NN], s_lower[NN];
    __shared__ float s_b[MM], s_c[MM], s_e2[MM], s_ax[MM], s_w[MM];
    __shared__ __align__(16) float s_part[4][NN];
    __shared__ float s_red[MM];
    __shared__ unsigned s_mask;
    __shared__ float s_t0;

    cg::grid_group grid = cg::this_grid();

    s_xraw[t]  = xraw_g[p*NN + t];
    s_lower[t] = lower_g[p*NN + t];
    if (t < MM) s_b[t] = b_g[p*MM + t];
    __syncthreads();

    // ---- A into registers (only global read of A in the whole kernel) ----
    float4 a[32];
    #pragma unroll
    for (int i = 0; i < 32; ++i)
        a[i] = ((const float4*)(A + (size_t)(wave*32 + i) * NN))[lane];

    // ---- row stats: ssq -> rownorm, rowsum, A.lower ----
    {
        const float4 lo4 = ((const float4*)s_lower)[lane];
        #pragma unroll
        for (int i = 0; i < 32; ++i) {
            float ssq = a[i].x*a[i].x + a[i].y*a[i].y + a[i].z*a[i].z + a[i].w*a[i].w;
            float rs  = a[i].x + a[i].y + a[i].z + a[i].w;
            float al  = a[i].x*lo4.x + a[i].y*lo4.y + a[i].z*lo4.z + a[i].w*lo4.w;
            BFLY_ADD(ssq); BFLY_ADD(rs); BFLY_ADD(al);
            if (lane == 0) {
                const int m = wave*32 + i;
                s_part[0][m] = ssq; s_part[1][m] = rs; s_part[2][m] = al;
            }
        }
    }
    __syncthreads();

    if (t < MM) {
        const float r  = fmaxf(sqrtf(s_part[0][t]), 1e-12f);
        s_c[t]  = s_b[t] - EPS * r;               // unnormalized feasibility threshold
        s_e2[t] = 1e-12f * r;                     // unnormalized slack clamp
        const float adw = s_part[1][t] / r;
        const float sw  = (s_b[t] - s_part[2][t]) / r;
        s_red[t] = (adw > 0.f) ? (sw / fmaxf(adw, 1e-12f)) : INFINITY;
    }
    __syncthreads();
    if (t < 64) s_red[t] = fminf(s_red[t], s_red[t + 64]);
    __syncthreads();
    if (t < 32) s_red[t] = fminf(s_red[t], s_red[t + 32]);
    __syncthreads();
    if (t < 16) s_red[t] = fminf(s_red[t], s_red[t + 16]);
    __syncthreads();
    if (t < 8)  s_red[t] = fminf(s_red[t], s_red[t + 8]);
    __syncthreads();
    if (t < 4)  s_red[t] = fminf(s_red[t], s_red[t + 4]);
    __syncthreads();
    if (t == 0) {
        const float v = fminf(fminf(s_red[0], s_red[1]), fminf(s_red[2], s_red[3]));
        s_t0 = fmaxf(0.5f * v, 2.0f * EPS);
    }
    __syncthreads();
    const float t0 = s_t0;

    s_x[t] = s_lower[t] + t0;
    if (t < MM) s_ax[t] = s_part[2][t] + t0 * s_part[1][t];
    __syncthreads();

    // ---- feasibility repair branch (faithful; no-op for these inputs) ----
    {
        int ok = (s_x[t] >= s_lower[t] + EPS);
        if (t < MM) ok = ok && (s_ax[t] <= s_c[t]);
        const int feas = __syncthreads_and(ok);
        if (!feas) {
            s_x[t] = 0.5f * (fmaxf(s_x[t], 0.f) + s_lower[t]);
            __syncthreads();
            const float4 x4 = ((const float4*)s_x)[lane];
            #pragma unroll
            for (int i = 0; i < 32; ++i) {
                float px = a[i].x*x4.x + a[i].y*x4.y + a[i].z*x4.z + a[i].w*x4.w;
                BFLY_ADD(px);
                if (lane == 0) s_ax[wave*32 + i] = px;
            }
            __syncthreads();
        }
    }

    const float mystep = (lane < MAX_LS) ? ldexpf(1.0f, -lane) : 0.0f;

    for (int k = 0; k < K_ITER; ++k) {
        if (t < MM) s_w[t] = MU / fmaxf(s_b[t] - s_ax[t], s_e2[t]);
        if (t == 0) s_mask = 0xFFFFFFFFu;
        __syncthreads();

        // -- pass 1: column partials of A^T w (registers only) --
        float4 pp = make_float4(0.f, 0.f, 0.f, 0.f);
        #pragma unroll
        for (int i = 0; i < 32; ++i) {
            const float wm = s_w[wave*32 + i];
            pp.x = fmaf(a[i].x, wm, pp.x);
            pp.y = fmaf(a[i].y, wm, pp.y);
            pp.z = fmaf(a[i].z, wm, pp.z);
            pp.w = fmaf(a[i].w, wm, pp.w);
        }
        ((float4*)s_part[wave])[lane] = pp;
        __syncthreads();

        // -- gradient + n-side line-search mask (thread == column) --
        {
            const float g  = (s_part[0][t] + s_part[1][t]) + (s_part[2][t] + s_part[3][t]);
            const float xt = s_x[t];
            const float gr = (xt - s_xraw[t]) + g + MU / fmaxf(xt - s_lower[t], 1e-12f);
            s_grad[t] = gr;

            unsigned mn = 0u;
            const float loe = s_lower[t] + EPS;
            float st = 1.0f;
            #pragma unroll
            for (int l = 0; l < MAX_LS; ++l) {
                if (xt - st * gr >= loe) mn |= (1u << l);
                st *= 0.5f;
            }
            mn &= __shfl_xor(mn, 1);  mn &= __shfl_xor(mn, 2);
            mn &= __shfl_xor(mn, 4);  mn &= __shfl_xor(mn, 8);
            mn &= __shfl_xor(mn, 16); mn &= __shfl_xor(mn, 32);
            if (lane == 0) atomicAnd(&s_mask, mn);
        }
        __syncthreads();   // s_grad complete; s_part free

        // -- pass 2: Ag, fresh Ax from registers; m-side mask --
        {
            const float4 g4 = ((const float4*)s_grad)[lane];
            const float4 x4 = ((const float4*)s_x)[lane];
            unsigned mm = 0xFFFFFFFFu;
            #pragma unroll
            for (int i = 0; i < 32; ++i) {
                const int m = wave*32 + i;
                float pg = a[i].x*g4.x + a[i].y*g4.y + a[i].z*g4.z + a[i].w*g4.w;
                float px = a[i].x*x4.x + a[i].y*x4.y + a[i].z*x4.z + a[i].w*x4.w;
                BFLY_ADD(pg); BFLY_ADD(px);
                bool okm = true;
                if (lane < MAX_LS) okm = (px - mystep * pg) <= s_c[m];
                const unsigned long long bal = __ballot(okm);
                mm &= ((unsigned)bal | ~FULLMASK);
                if (lane == 0) { s_part[0][m] = px; s_part[1][m] = pg; }
            }
            if (lane == 0) atomicAnd(&s_mask, mm);
        }
        __syncthreads();

        if (t == 0) atomicAnd(&gmask[k], s_mask & FULLMASK);
        grid.sync();

        const unsigned gm = ((volatile unsigned*)gmask)[k];
        const float step = gm ? ldexpf(1.0f, -(__ffs(gm) - 1)) : 0.0f;
        s_x[t] -= step * s_grad[t];
        if (t < MM) s_ax[t] = s_part[0][t] - step * s_part[1][t];
        __syncthreads();
    }

    out_g[p*NN + t] = fmaxf(s_x[t], 0.0f);
}

// ================= fallback path (round-2 kernels, proven 851 us) =========
__global__ __launch_bounds__(1024, 8)
void lbp_init(const float* __restrict__ A_g,
              const float* __restrict__ b_g,
              const float* __restrict__ lower_g,
              float* __restrict__ ws,
              unsigned* __restrict__ gmask)
{
    const int p    = blockIdx.x;
    const int t    = threadIdx.x;
    const int lane = t & 63;
    const int wave = t >> 6;

    const float* A  = A_g + (size_t)p * (MM * NN);
    const float* bb = b_g + p * MM;

    __shared__ __align__(16) float s_lower[NN];
    __shared__ __align__(16) float s_x[NN];
    __shared__ float s_ssq[MM], s_rs[MM], s_al[MM];
    __shared__ float s_red[MM];
    __shared__ float s_t0;

    if (t < NN) s_lower[t] = lower_g[p * NN + t];
    __syncthreads();

    {
        const float4 lo4 = ((const float4*)s_lower)[lane];
        #pragma unroll 2
        for (int i = 0; i < 8; ++i) {
            const int m = wave * 8 + i;
            const float4 a4 = ((const float4*)(A + m * NN))[lane];
            float ssq = a4.x*a4.x + a4.y*a4.y + a4.z*a4.z + a4.w*a4.w;
            float rs  = a4.x + a4.y + a4.z + a4.w;
            float al  = a4.x*lo4.x + a4.y*lo4.y + a4.z*lo4.z + a4.w*lo4.w;
            BFLY_ADD(ssq); BFLY_ADD(rs); BFLY_ADD(al);
            if (lane == 0) { s_ssq[m] = ssq; s_rs[m] = rs; s_al[m] = al; }
        }
    }
    __syncthreads();

    if (t < MM) {
        const float r = fmaxf(sqrtf(s_ssq[t]), 1e-12f);
        s_ssq[t] = r;
        ws[OR_ + p * MM + t] = r;
        const float adw = s_rs[t] / r;
        const float sw  = (bb[t] - s_al[t]) / r;
        s_red[t] = (adw > 0.f) ? (sw / fmaxf(adw, 1e-12f)) : INFINITY;
    }
    __syncthreads();
    if (t < 64) s_red[t] = fminf(s_red[t], s_red[t + 64]);
    __syncthreads();
    if (t < 32) s_red[t] = fminf(s_red[t], s_red[t + 32]);
    __syncthreads();
    if (t < 16) s_red[t] = fminf(s_red[t], s_red[t + 16]);
    __syncthreads();
    if (t < 8)  s_red[t] = fminf(s_red[t], s_red[t + 8]);
    __syncthreads();
    if (t < 4)  s_red[t] = fminf(s_red[t], s_red[t + 4]);
    __syncthreads();
    if (t == 0) s_t0 = fmaxf(0.5f * fminf(fminf(s_red[0], s_red[1]),
                                          fminf(s_red[2], s_red[3])), 2.0f * EPS);
    __syncthreads();
    const float t0 = s_t0;

    float x = 0.f, ax = 0.f;
    if (t < NN) x  = s_lower[t] + t0;
    if (t < MM) ax = s_al[t] + t0 * s_rs[t];

    int ok = 1;
    if (t < MM) ok = ok && (ax <= bb[t] - EPS * s_ssq[t]);
    if (t < NN) ok = ok && (x >= s_lower[t] + EPS);
    const int feas = __syncthreads_and(ok);
    if (!feas) {
        if (t < NN) { x = 0.5f * (fmaxf(x, 0.f) + s_lower[t]); s_x[t] = x; }
        __syncthreads();
        const float4 x4 = ((const float4*)s_x)[lane];
        for (int i = 0; i < 8; ++i) {
            const int m = wave * 8 + i;
            const float4 a4 = ((const float4*)(A + m * NN))[lane];
            float px = a4.x*x4.x + a4.y*x4.y + a4.z*x4.z + a4.w*x4.w;
            BFLY_ADD(px);
            if (lane == 0) s_al[m] = px;
        }
        __syncthreads();
        if (t < MM) ax = s_al[t];
    }

    if (t < NN) ws[OX  + p * NN + t] = x;
    if (t < MM) ws[OAX + p * MM + t] = ax;
    if (p == 0 && t < K_ITER) gmask[t] = FULLMASK;
}

__global__ __launch_bounds__(1024, 8)
void lbp_iter(const float* __restrict__ A_g,
              const float* __restrict__ b_g,
              const float* __restrict__ xraw_g,
              const float* __restrict__ lower_g,
              float* __restrict__ ws,
              unsigned* __restrict__ gmask,
              int k)
{
    const int p    = blockIdx.x;
    const int t    = threadIdx.x;
    const int lane = t & 63;
    const int wave = t >> 6;

    const float* A  = A_g + (size_t)p * (MM * NN);
    const float* bb = b_g + p * MM;

    __shared__ __align__(16) float s_x[NN];
    __shared__ __align__(16) float s_grad[NN];
    __shared__ __align__(16) float s_xraw[NN];
    __shared__ __align__(16) float s_lower[NN];
    __shared__ float s_w[MM], s_c[MM];
    __shared__ float s_part[4][NN];
    __shared__ unsigned s_mask;

    if (t == 0) s_mask = 0xFFFFFFFFu;
    if (t < NN) { s_xraw[t] = xraw_g[p * NN + t]; s_lower[t] = lower_g[p * NN + t]; }

    float step = 0.f;
    if (k > 0) {
        const unsigned gm = gmask[k - 1];
        step = gm ? ldexpf(1.0f, -(__ffs(gm) - 1)) : 0.0f;
    }
    if (t < NN) {
        float x = ws[OX + p * NN + t];
        if (k > 0) { x -= step * ws[OG + p * NN + t]; ws[OX + p * NN + t] = x; }
        s_x[t] = x;
    }
    if (t < MM) {
        float ax = ws[OAX + p * MM + t];
        if (k > 0) ax -= step * ws[OAG + p * MM + t];
        const float r  = ws[OR_ + p * MM + t];
        const float bm = bb[t];
        s_c[t] = bm - EPS * r;
        s_w[t] = MU / fmaxf(bm - ax, 1e-12f * r);
    }
    __syncthreads();

    {
        const int col = t & (NN - 1);
        const int q   = t >> 8;
        const float* Ac = A + (size_t)(q * 32) * NN + col;
        float g = 0.f;
        #pragma unroll 8
        for (int j = 0; j < 32; ++j) g = fmaf(Ac[(size_t)j * NN], s_w[q * 32 + j], g);
        s_part[q][col] = g;
    }
    __syncthreads();

    if (t < NN) {
        const float g  = s_part[0][t] + s_part[1][t] + s_part[2][t] + s_part[3][t];
        const float xt = s_x[t];
        const float gr = (xt - s_xraw[t]) + g + MU / fmaxf(xt - s_lower[t], 1e-12f);
        s_grad[t] = gr;
        ws[OG + p * NN + t] = gr;

        unsigned mn = 0u;
        const float loe = s_lower[t] + EPS;
        float st = 1.0f;
        #pragma unroll
        for (int l = 0; l < MAX_LS; ++l) {
            if (xt - st * gr >= loe) mn |= (1u << l);
            st *= 0.5f;
        }
        mn &= __shfl_xor(mn, 1);  mn &= __shfl_xor(mn, 2);
        mn &= __shfl_xor(mn, 4);  mn &= __shfl_xor(mn, 8);
        mn &= __shfl_xor(mn, 16); mn &= __shfl_xor(mn, 32);
        if (lane == 0) atomicAnd(&s_mask, mn);
    }
    __syncthreads();

    {
        const float4 g4 = ((const float4*)s_grad)[lane];
        const float4 x4 = ((const float4*)s_x)[lane];
        const float mystep = (lane < MAX_LS) ? ldexpf(1.0f, -lane) : 0.0f;
        unsigned mm = 0xFFFFFFFFu;
        #pragma unroll 2
        for (int i = 0; i < 8; ++i) {
            const int m = wave * 8 + i;
            const float4 a4 = ((const float4*)(A + m * NN))[lane];
            float pg = a4.x*g4.x + a4.y*g4.y + a4.z*g4.z + a4.w*g4.w;
            float px = a4.x*x4.x + a4.y*x4.y + a4.z*x4.z + a4.w*x4.w;
            BFLY_ADD(pg); BFLY_ADD(px);
            bool okm = true;
            if (lane < MAX_LS) okm = (px - mystep * pg) <= s_c[m];
            const unsigned long long bal = __ballot(okm);
            mm &= ((unsigned)bal | ~FULLMASK);
            if (lane == 0) { ws[OAG + p * MM + m] = pg; ws[OAX + p * MM + m] = px; }
        }
        if (lane == 0) atomicAnd(&s_mask, mm);
    }
    __syncthreads();

    if (t == 0) atomicAnd(&gmask[k], s_mask & FULLMASK);
}

__global__ __launch_bounds__(256)
void lbp_fin(const float* __restrict__ ws,
             const unsigned* __restrict__ gmask,
             float* __restrict__ out_g)
{
    const int p = blockIdx.x;
    const int t = threadIdx.x;
    const unsigned gm = gmask[K_ITER - 1];
    const float step = gm ? ldexpf(1.0f, -(__ffs(gm) - 1)) : 0.0f;
    const float x = ws[OX + p * NN + t] - step * ws[OG + p * NN + t];
    out_g[p * NN + t] = fmaxf(x, 0.0f);
}

// -------------------------------------------------------------- launch ----
extern "C" void kernel_launch(void* const* d_in, const int* in_sizes, int n_in,
                              void* d_out, int out_size, void* d_ws, size_t ws_size,
                              hipStream_t stream) {
    const float* xraw  = (const float*)d_in[0];
    const float* A     = (const float*)d_in[1];
    const float* b     = (const float*)d_in[2];
    const float* lower = (const float*)d_in[3];
    float* out = (float*)d_out;

    unsigned* gmask = (unsigned*)d_ws;                      // 32 uints
    float* ws2 = (float*)((char*)d_ws + 256);               // fallback arrays

    lbp_gmask_init<<<1, 64, 0, stream>>>(gmask);

    void* args[] = { (void*)&xraw, (void*)&A, (void*)&b, (void*)&lower,
                     (void*)&out, (void*)&gmask };
    hipError_t err = hipLaunchCooperativeKernel((const void*)lbp_persist,
                                                dim3(NPROB), dim3(256),
                                                args, 0, stream);
    if (err != hipSuccess) {
        // deterministic fallback: proven multi-kernel path (~851 us)
        lbp_init<<<NPROB, 1024, 0, stream>>>(A, b, lower, ws2, gmask);
        for (int k = 0; k < K_ITER; ++k)
            lbp_iter<<<NPROB, 1024, 0, stream>>>(A, b, xraw, lower, ws2, gmask, k);
        lbp_fin<<<NPROB, 256, 0, stream>>>(ws2, gmask, out);
    }
}

// Round 5
// 1088.679 us; speedup vs baseline: 1.7440x; 1.7440x over previous
//
#include <hip/hip_runtime.h>

#define K_ITER   30
#define MU       0.01f
#define EPS      1e-6f
#define MAX_LS   25
#define FULLMASK 0x01FFFFFFu
#define MM       128
#define NN       256
#define NPROB    512

// ---- d_ws layout (bytes) ----
// [0,128)    gmask   unsigned[32]
// [128,256)  cnt     unsigned[32]
// [256,384)  done    unsigned[32]   (0 = not ready; else 0x80000000|gm)
// [1024,...) fallback-path float arrays
#define OX   ((size_t)0)
#define OG   ((size_t)(NPROB*NN))
#define OAX  ((size_t)(2*NPROB*NN))
#define OAG  (OAX + (size_t)(NPROB*MM))
#define OR_  (OAG + (size_t)(NPROB*MM))

#define BFLY_ADD(v) do { \
    v += __shfl_xor(v, 1);  v += __shfl_xor(v, 2);  v += __shfl_xor(v, 4); \
    v += __shfl_xor(v, 8);  v += __shfl_xor(v, 16); v += __shfl_xor(v, 32); } while (0)

__global__ void lbp_ctrl_init(unsigned* __restrict__ gmask,
                              unsigned* __restrict__ cnt,
                              unsigned* __restrict__ done) {
    const int t = threadIdx.x;
    if (t < 32) { gmask[t] = FULLMASK; cnt[t] = 0u; done[t] = 0u; }
}

// ================= persistent cooperative kernel (primary path) ===========
// 512 blocks x 256 threads (4 waves), 2 blocks/CU. Wave w owns rows
// 32w..32w+31; lane l owns cols 4l..4l+3. A = 32 float4 = 128 VGPRs/thread.
// NO function calls in the body (inline barrier) so A stays register-resident.
__global__ __launch_bounds__(256, 2)
void lbp_persist(const float* __restrict__ xraw_g,
                 const float* __restrict__ A_g,
                 const float* __restrict__ b_g,
                 const float* __restrict__ lower_g,
                 float* __restrict__ out_g,
                 unsigned* __restrict__ gmask,
                 unsigned* __restrict__ cnt,
                 unsigned* __restrict__ done)
{
    const int p    = blockIdx.x;
    const int t    = threadIdx.x;      // 0..255 (== column n)
    const int lane = t & 63;
    const int wave = t >> 6;           // 0..3

    const float* A = A_g + (size_t)p * MM * NN;

    __shared__ __align__(16) float s_x[NN], s_grad[NN], s_xraw[NN], s_lower[NN];
    __shared__ float s_b[MM], s_c[MM], s_e2[MM], s_ax[MM], s_w[MM];
    __shared__ __align__(16) float s_part[4][NN];
    __shared__ float s_red[MM];
    __shared__ unsigned s_mask, s_done;
    __shared__ float s_t0;

    s_xraw[t]  = xraw_g[p*NN + t];
    s_lower[t] = lower_g[p*NN + t];
    if (t < MM) s_b[t] = b_g[p*MM + t];
    __syncthreads();

    // ---- A into registers (only global read of A in the whole kernel) ----
    float4 a[32];
    #pragma unroll
    for (int i = 0; i < 32; ++i)
        a[i] = ((const float4*)(A + (size_t)(wave*32 + i) * NN))[lane];

    // ---- row stats: ssq -> rownorm, rowsum, A.lower ----
    {
        const float4 lo4 = ((const float4*)s_lower)[lane];
        #pragma unroll
        for (int i = 0; i < 32; ++i) {
            float ssq = a[i].x*a[i].x + a[i].y*a[i].y + a[i].z*a[i].z + a[i].w*a[i].w;
            float rs  = a[i].x + a[i].y + a[i].z + a[i].w;
            float al  = a[i].x*lo4.x + a[i].y*lo4.y + a[i].z*lo4.z + a[i].w*lo4.w;
            BFLY_ADD(ssq); BFLY_ADD(rs); BFLY_ADD(al);
            if (lane == 0) {
                const int m = wave*32 + i;
                s_part[0][m] = ssq; s_part[1][m] = rs; s_part[2][m] = al;
            }
        }
    }
    __syncthreads();

    if (t < MM) {
        const float r  = fmaxf(sqrtf(s_part[0][t]), 1e-12f);
        s_c[t]  = s_b[t] - EPS * r;               // unnormalized feasibility threshold
        s_e2[t] = 1e-12f * r;                     // unnormalized slack clamp
        const float adw = s_part[1][t] / r;
        const float sw  = (s_b[t] - s_part[2][t]) / r;
        s_red[t] = (adw > 0.f) ? (sw / fmaxf(adw, 1e-12f)) : INFINITY;
    }
    __syncthreads();
    if (t < 64) s_red[t] = fminf(s_red[t], s_red[t + 64]);
    __syncthreads();
    if (t < 32) s_red[t] = fminf(s_red[t], s_red[t + 32]);
    __syncthreads();
    if (t < 16) s_red[t] = fminf(s_red[t], s_red[t + 16]);
    __syncthreads();
    if (t < 8)  s_red[t] = fminf(s_red[t], s_red[t + 8]);
    __syncthreads();
    if (t < 4)  s_red[t] = fminf(s_red[t], s_red[t + 4]);
    __syncthreads();
    if (t == 0) {
        const float v = fminf(fminf(s_red[0], s_red[1]), fminf(s_red[2], s_red[3]));
        s_t0 = fmaxf(0.5f * v, 2.0f * EPS);
    }
    __syncthreads();
    const float t0 = s_t0;

    s_x[t] = s_lower[t] + t0;
    if (t < MM) s_ax[t] = s_part[2][t] + t0 * s_part[1][t];
    __syncthreads();

    // ---- feasibility repair branch (faithful; no-op for these inputs) ----
    {
        int ok = (s_x[t] >= s_lower[t] + EPS);
        if (t < MM) ok = ok && (s_ax[t] <= s_c[t]);
        const int feas = __syncthreads_and(ok);
        if (!feas) {
            s_x[t] = 0.5f * (fmaxf(s_x[t], 0.f) + s_lower[t]);
            __syncthreads();
            const float4 x4 = ((const float4*)s_x)[lane];
            #pragma unroll
            for (int i = 0; i < 32; ++i) {
                float px = a[i].x*x4.x + a[i].y*x4.y + a[i].z*x4.z + a[i].w*x4.w;
                BFLY_ADD(px);
                if (lane == 0) s_ax[wave*32 + i] = px;
            }
            __syncthreads();
        }
    }

    const float mystep = (lane < MAX_LS) ? ldexpf(1.0f, -lane) : 0.0f;

    for (int k = 0; k < K_ITER; ++k) {
        if (t < MM) s_w[t] = MU / fmaxf(s_b[t] - s_ax[t], s_e2[t]);
        if (t == 0) s_mask = 0xFFFFFFFFu;
        __syncthreads();

        // -- pass 1: column partials of A^T w (registers only) --
        float4 pp = make_float4(0.f, 0.f, 0.f, 0.f);
        #pragma unroll
        for (int i = 0; i < 32; ++i) {
            const float wm = s_w[wave*32 + i];
            pp.x = fmaf(a[i].x, wm, pp.x);
            pp.y = fmaf(a[i].y, wm, pp.y);
            pp.z = fmaf(a[i].z, wm, pp.z);
            pp.w = fmaf(a[i].w, wm, pp.w);
        }
        ((float4*)s_part[wave])[lane] = pp;
        __syncthreads();

        // -- gradient + n-side line-search mask (thread == column) --
        {
            const float g  = (s_part[0][t] + s_part[1][t]) + (s_part[2][t] + s_part[3][t]);
            const float xt = s_x[t];
            const float gr = (xt - s_xraw[t]) + g + MU / fmaxf(xt - s_lower[t], 1e-12f);
            s_grad[t] = gr;

            unsigned mn = 0u;
            const float loe = s_lower[t] + EPS;
            float st = 1.0f;
            #pragma unroll
            for (int l = 0; l < MAX_LS; ++l) {
                if (xt - st * gr >= loe) mn |= (1u << l);
                st *= 0.5f;
            }
            mn &= __shfl_xor(mn, 1);  mn &= __shfl_xor(mn, 2);
            mn &= __shfl_xor(mn, 4);  mn &= __shfl_xor(mn, 8);
            mn &= __shfl_xor(mn, 16); mn &= __shfl_xor(mn, 32);
            if (lane == 0) atomicAnd(&s_mask, mn);
        }
        __syncthreads();   // s_grad complete; s_part free

        // -- pass 2: Ag, fresh Ax from registers; m-side mask --
        {
            const float4 g4 = ((const float4*)s_grad)[lane];
            const float4 x4 = ((const float4*)s_x)[lane];
            unsigned mm = 0xFFFFFFFFu;
            #pragma unroll
            for (int i = 0; i < 32; ++i) {
                const int m = wave*32 + i;
                float pg = a[i].x*g4.x + a[i].y*g4.y + a[i].z*g4.z + a[i].w*g4.w;
                float px = a[i].x*x4.x + a[i].y*x4.y + a[i].z*x4.z + a[i].w*x4.w;
                BFLY_ADD(pg); BFLY_ADD(px);
                bool okm = true;
                if (lane < MAX_LS) okm = (px - mystep * pg) <= s_c[m];
                const unsigned long long bal = __ballot(okm);
                mm &= ((unsigned)bal | ~FULLMASK);
                if (lane == 0) { s_part[0][m] = px; s_part[1][m] = pg; }
            }
            if (lane == 0) atomicAnd(&s_mask, mm);
        }
        __syncthreads();

        // -- inline global AND-barrier (no function calls => A stays in VGPRs) --
        if (t == 0) {
            atomicAnd(&gmask[k], s_mask & FULLMASK);
            __threadfence();
            const unsigned old = atomicAdd(&cnt[k], 1u);
            if (old == NPROB - 1) {
                __threadfence();
                const unsigned gm = __hip_atomic_load(&gmask[k], __ATOMIC_RELAXED,
                                                      __HIP_MEMORY_SCOPE_AGENT);
                const unsigned v = 0x80000000u | gm;
                __hip_atomic_store(&done[k], v, __ATOMIC_RELEASE,
                                   __HIP_MEMORY_SCOPE_AGENT);
                s_done = v;
            } else {
                unsigned v;
                do {
                    __builtin_amdgcn_s_sleep(1);
                    v = __hip_atomic_load(&done[k], __ATOMIC_ACQUIRE,
                                          __HIP_MEMORY_SCOPE_AGENT);
                } while (v == 0u);
                s_done = v;
            }
        }
        __syncthreads();

        const unsigned gm = s_done & FULLMASK;
        const float step = gm ? ldexpf(1.0f, -(__ffs(gm) - 1)) : 0.0f;
        s_x[t] -= step * s_grad[t];
        if (t < MM) s_ax[t] = s_part[0][t] - step * s_part[1][t];
        __syncthreads();
    }

    out_g[p*NN + t] = fmaxf(s_x[t], 0.0f);
}

// ================= fallback path (round-2 kernels, proven 851 us) =========
__global__ __launch_bounds__(1024, 8)
void lbp_init(const float* __restrict__ A_g,
              const float* __restrict__ b_g,
              const float* __restrict__ lower_g,
              float* __restrict__ ws,
              unsigned* __restrict__ gmask)
{
    const int p    = blockIdx.x;
    const int t    = threadIdx.x;
    const int lane = t & 63;
    const int wave = t >> 6;

    const float* A  = A_g + (size_t)p * (MM * NN);
    const float* bb = b_g + p * MM;

    __shared__ __align__(16) float s_lower[NN];
    __shared__ __align__(16) float s_x[NN];
    __shared__ float s_ssq[MM], s_rs[MM], s_al[MM];
    __shared__ float s_red[MM];
    __shared__ float s_t0;

    if (t < NN) s_lower[t] = lower_g[p * NN + t];
    __syncthreads();

    {
        const float4 lo4 = ((const float4*)s_lower)[lane];
        #pragma unroll 2
        for (int i = 0; i < 8; ++i) {
            const int m = wave * 8 + i;
            const float4 a4 = ((const float4*)(A + m * NN))[lane];
            float ssq = a4.x*a4.x + a4.y*a4.y + a4.z*a4.z + a4.w*a4.w;
            float rs  = a4.x + a4.y + a4.z + a4.w;
            float al  = a4.x*lo4.x + a4.y*lo4.y + a4.z*lo4.z + a4.w*lo4.w;
            BFLY_ADD(ssq); BFLY_ADD(rs); BFLY_ADD(al);
            if (lane == 0) { s_ssq[m] = ssq; s_rs[m] = rs; s_al[m] = al; }
        }
    }
    __syncthreads();

    if (t < MM) {
        const float r = fmaxf(sqrtf(s_ssq[t]), 1e-12f);
        s_ssq[t] = r;
        ws[OR_ + p * MM + t] = r;
        const float adw = s_rs[t] / r;
        const float sw  = (bb[t] - s_al[t]) / r;
        s_red[t] = (adw > 0.f) ? (sw / fmaxf(adw, 1e-12f)) : INFINITY;
    }
    __syncthreads();
    if (t < 64) s_red[t] = fminf(s_red[t], s_red[t + 64]);
    __syncthreads();
    if (t < 32) s_red[t] = fminf(s_red[t], s_red[t + 32]);
    __syncthreads();
    if (t < 16) s_red[t] = fminf(s_red[t], s_red[t + 16]);
    __syncthreads();
    if (t < 8)  s_red[t] = fminf(s_red[t], s_red[t + 8]);
    __syncthreads();
    if (t < 4)  s_red[t] = fminf(s_red[t], s_red[t + 4]);
    __syncthreads();
    if (t == 0) s_t0 = fmaxf(0.5f * fminf(fminf(s_red[0], s_red[1]),
                                          fminf(s_red[2], s_red[3])), 2.0f * EPS);
    __syncthreads();
    const float t0 = s_t0;

    float x = 0.f, ax = 0.f;
    if (t < NN) x  = s_lower[t] + t0;
    if (t < MM) ax = s_al[t] + t0 * s_rs[t];

    int ok = 1;
    if (t < MM) ok = ok && (ax <= bb[t] - EPS * s_ssq[t]);
    if (t < NN) ok = ok && (x >= s_lower[t] + EPS);
    const int feas = __syncthreads_and(ok);
    if (!feas) {
        if (t < NN) { x = 0.5f * (fmaxf(x, 0.f) + s_lower[t]); s_x[t] = x; }
        __syncthreads();
        const float4 x4 = ((const float4*)s_x)[lane];
        for (int i = 0; i < 8; ++i) {
            const int m = wave * 8 + i;
            const float4 a4 = ((const float4*)(A + m * NN))[lane];
            float px = a4.x*x4.x + a4.y*x4.y + a4.z*x4.z + a4.w*x4.w;
            BFLY_ADD(px);
            if (lane == 0) s_al[m] = px;
        }
        __syncthreads();
        if (t < MM) ax = s_al[t];
    }

    if (t < NN) ws[OX  + p * NN + t] = x;
    if (t < MM) ws[OAX + p * MM + t] = ax;
    if (p == 0 && t < K_ITER) gmask[t] = FULLMASK;
}

__global__ __launch_bounds__(1024, 8)
void lbp_iter(const float* __restrict__ A_g,
              const float* __restrict__ b_g,
              const float* __restrict__ xraw_g,
              const float* __restrict__ lower_g,
              float* __restrict__ ws,
              unsigned* __restrict__ gmask,
              int k)
{
    const int p    = blockIdx.x;
    const int t    = threadIdx.x;
    const int lane = t & 63;
    const int wave = t >> 6;

    const float* A  = A_g + (size_t)p * (MM * NN);
    const float* bb = b_g + p * MM;

    __shared__ __align__(16) float s_x[NN];
    __shared__ __align__(16) float s_grad[NN];
    __shared__ __align__(16) float s_xraw[NN];
    __shared__ __align__(16) float s_lower[NN];
    __shared__ float s_w[MM], s_c[MM];
    __shared__ float s_part[4][NN];
    __shared__ unsigned s_mask;

    if (t == 0) s_mask = 0xFFFFFFFFu;
    if (t < NN) { s_xraw[t] = xraw_g[p * NN + t]; s_lower[t] = lower_g[p * NN + t]; }

    float step = 0.f;
    if (k > 0) {
        const unsigned gm = gmask[k - 1];
        step = gm ? ldexpf(1.0f, -(__ffs(gm) - 1)) : 0.0f;
    }
    if (t < NN) {
        float x = ws[OX + p * NN + t];
        if (k > 0) { x -= step * ws[OG + p * NN + t]; ws[OX + p * NN + t] = x; }
        s_x[t] = x;
    }
    if (t < MM) {
        float ax = ws[OAX + p * MM + t];
        if (k > 0) ax -= step * ws[OAG + p * MM + t];
        const float r  = ws[OR_ + p * MM + t];
        const float bm = bb[t];
        s_c[t] = bm - EPS * r;
        s_w[t] = MU / fmaxf(bm - ax, 1e-12f * r);
    }
    __syncthreads();

    {
        const int col = t & (NN - 1);
        const int q   = t >> 8;
        const float* Ac = A + (size_t)(q * 32) * NN + col;
        float g = 0.f;
        #pragma unroll 8
        for (int j = 0; j < 32; ++j) g = fmaf(Ac[(size_t)j * NN], s_w[q * 32 + j], g);
        s_part[q][col] = g;
    }
    __syncthreads();

    if (t < NN) {
        const float g  = s_part[0][t] + s_part[1][t] + s_part[2][t] + s_part[3][t];
        const float xt = s_x[t];
        const float gr = (xt - s_xraw[t]) + g + MU / fmaxf(xt - s_lower[t], 1e-12f);
        s_grad[t] = gr;
        ws[OG + p * NN + t] = gr;

        unsigned mn = 0u;
        const float loe = s_lower[t] + EPS;
        float st = 1.0f;
        #pragma unroll
        for (int l = 0; l < MAX_LS; ++l) {
            if (xt - st * gr >= loe) mn |= (1u << l);
            st *= 0.5f;
        }
        mn &= __shfl_xor(mn, 1);  mn &= __shfl_xor(mn, 2);
        mn &= __shfl_xor(mn, 4);  mn &= __shfl_xor(mn, 8);
        mn &= __shfl_xor(mn, 16); mn &= __shfl_xor(mn, 32);
        if (lane == 0) atomicAnd(&s_mask, mn);
    }
    __syncthreads();

    {
        const float4 g4 = ((const float4*)s_grad)[lane];
        const float4 x4 = ((const float4*)s_x)[lane];
        const float mystep = (lane < MAX_LS) ? ldexpf(1.0f, -lane) : 0.0f;
        unsigned mm = 0xFFFFFFFFu;
        #pragma unroll 2
        for (int i = 0; i < 8; ++i) {
            const int m = wave * 8 + i;
            const float4 a4 = ((const float4*)(A + m * NN))[lane];
            float pg = a4.x*g4.x + a4.y*g4.y + a4.z*g4.z + a4.w*g4.w;
            float px = a4.x*x4.x + a4.y*x4.y + a4.z*x4.z + a4.w*x4.w;
            BFLY_ADD(pg); BFLY_ADD(px);
            bool okm = true;
            if (lane < MAX_LS) okm = (px - mystep * pg) <= s_c[m];
            const unsigned long long bal = __ballot(okm);
            mm &= ((unsigned)bal | ~FULLMASK);
            if (lane == 0) { ws[OAG + p * MM + m] = pg; ws[OAX + p * MM + m] = px; }
        }
        if (lane == 0) atomicAnd(&s_mask, mm);
    }
    __syncthreads();

    if (t == 0) atomicAnd(&gmask[k], s_mask & FULLMASK);
}

__global__ __launch_bounds__(256)
void lbp_fin(const float* __restrict__ ws,
             const unsigned* __restrict__ gmask,
             float* __restrict__ out_g)
{
    const int p = blockIdx.x;
    const int t = threadIdx.x;
    const unsigned gm = gmask[K_ITER - 1];
    const float step = gm ? ldexpf(1.0f, -(__ffs(gm) - 1)) : 0.0f;
    const float x = ws[OX + p * NN + t] - step * ws[OG + p * NN + t];
    out_g[p * NN + t] = fmaxf(x, 0.0f);
}

// -------------------------------------------------------------- launch ----
extern "C" void kernel_launch(void* const* d_in, const int* in_sizes, int n_in,
                              void* d_out, int out_size, void* d_ws, size_t ws_size,
                              hipStream_t stream) {
    const float* xraw  = (const float*)d_in[0];
    const float* A     = (const float*)d_in[1];
    const float* b     = (const float*)d_in[2];
    const float* lower = (const float*)d_in[3];
    float* out = (float*)d_out;

    unsigned* gmask = (unsigned*)d_ws;
    unsigned* cnt   = (unsigned*)((char*)d_ws + 128);
    unsigned* done  = (unsigned*)((char*)d_ws + 256);
    float* ws2 = (float*)((char*)d_ws + 1024);

    lbp_ctrl_init<<<1, 64, 0, stream>>>(gmask, cnt, done);

    void* args[] = { (void*)&xraw, (void*)&A, (void*)&b, (void*)&lower,
                     (void*)&out, (void*)&gmask, (void*)&cnt, (void*)&done };
    hipError_t err = hipLaunchCooperativeKernel((const void*)lbp_persist,
                                                dim3(NPROB), dim3(256),
                                                args, 0, stream);
    if (err != hipSuccess) {
        // deterministic fallback: proven multi-kernel path (~851 us)
        lbp_init<<<NPROB, 1024, 0, stream>>>(A, b, lower, ws2, gmask);
        for (int k = 0; k < K_ITER; ++k)
            lbp_iter<<<NPROB, 1024, 0, stream>>>(A, b, xraw, lower, ws2, gmask, k);
        lbp_fin<<<NPROB, 256, 0, stream>>>(ws2, gmask, out);
    }
}

// Round 6
// 1084.984 us; speedup vs baseline: 1.7499x; 1.0034x over previous
//
#include <hip/hip_runtime.h>

#define K_ITER   30
#define MU       0.01f
#define EPS      1e-6f
#define MAX_LS   25
#define FULLMASK 0x01FFFFFFu
#define MM       128
#define NN       256
#define NPROB    512

// ---- d_ws layout (bytes) ----
// [0,128)    gmask   unsigned[32]
// [128,256)  cnt     unsigned[32]
// [256,384)  done    unsigned[32]   (0 = not ready; else 0x80000000|gm)
// [1024,...) fallback-path float arrays
#define OX   ((size_t)0)
#define OG   ((size_t)(NPROB*NN))
#define OAX  ((size_t)(2*NPROB*NN))
#define OAG  (OAX + (size_t)(NPROB*MM))
#define OR_  (OAG + (size_t)(NPROB*MM))

#define BFLY_ADD(v) do { \
    v += __shfl_xor(v, 1);  v += __shfl_xor(v, 2);  v += __shfl_xor(v, 4); \
    v += __shfl_xor(v, 8);  v += __shfl_xor(v, 16); v += __shfl_xor(v, 32); } while (0)

#define REPEAT32(X) \
    X(0)  X(1)  X(2)  X(3)  X(4)  X(5)  X(6)  X(7) \
    X(8)  X(9)  X(10) X(11) X(12) X(13) X(14) X(15) \
    X(16) X(17) X(18) X(19) X(20) X(21) X(22) X(23) \
    X(24) X(25) X(26) X(27) X(28) X(29) X(30) X(31)

__global__ void lbp_ctrl_init(unsigned* __restrict__ gmask,
                              unsigned* __restrict__ cnt,
                              unsigned* __restrict__ done) {
    const int t = threadIdx.x;
    if (t < 32) { gmask[t] = FULLMASK; cnt[t] = 0u; done[t] = 0u; }
}

// ================= persistent cooperative kernel (primary path) ===========
// 512 blocks x 256 threads (4 waves), 2 blocks/CU. Wave w owns rows
// 32w..32w+31; lane l owns cols 4l..4l+3. A = 32 NAMED float4 vars (no
// alloca -> guaranteed VGPR-resident; a[32] array was demoted to scratch
// by promote-alloca size limits in rounds 4-5: VGPR_Count stuck at 100).
__global__ __launch_bounds__(256, 2)
void lbp_persist(const float* __restrict__ xraw_g,
                 const float* __restrict__ A_g,
                 const float* __restrict__ b_g,
                 const float* __restrict__ lower_g,
                 float* __restrict__ out_g,
                 unsigned* __restrict__ gmask,
                 unsigned* __restrict__ cnt,
                 unsigned* __restrict__ done)
{
    const int p    = blockIdx.x;
    const int t    = threadIdx.x;      // 0..255 (== column n)
    const int lane = t & 63;
    const int wave = t >> 6;           // 0..3

    // row base: float4-granular pointer to A[wave*32 + i][lane*4]
    const float4* Arow = (const float4*)(A_g + (size_t)p * MM * NN)
                         + (size_t)(wave * 32) * (NN / 4) + lane;

    __shared__ __align__(16) float s_x[NN], s_grad[NN], s_xraw[NN], s_lower[NN];
    __shared__ float s_b[MM], s_c[MM], s_e2[MM], s_ax[MM], s_w[MM];
    __shared__ __align__(16) float s_part[4][NN];
    __shared__ float s_red[MM];
    __shared__ unsigned s_mask, s_done;
    __shared__ float s_t0;

    s_xraw[t]  = xraw_g[p*NN + t];
    s_lower[t] = lower_g[p*NN + t];
    if (t < MM) s_b[t] = b_g[p*MM + t];
    __syncthreads();

    // ---- A into named registers (only global read of A in the kernel) ----
#define DECL_A(i) float4 a##i = Arow[(i) * (NN / 4)];
    REPEAT32(DECL_A)
#undef DECL_A

    // ---- row stats: ssq -> rownorm, rowsum, A.lower ----
    {
        const float4 lo4 = ((const float4*)s_lower)[lane];
#define STAT_A(i) { \
        float _ssq = a##i.x*a##i.x + a##i.y*a##i.y + a##i.z*a##i.z + a##i.w*a##i.w; \
        float _rs  = a##i.x + a##i.y + a##i.z + a##i.w; \
        float _al  = a##i.x*lo4.x + a##i.y*lo4.y + a##i.z*lo4.z + a##i.w*lo4.w; \
        BFLY_ADD(_ssq); BFLY_ADD(_rs); BFLY_ADD(_al); \
        if (lane == 0) { const int _m = wave*32 + (i); \
            s_part[0][_m] = _ssq; s_part[1][_m] = _rs; s_part[2][_m] = _al; } }
        REPEAT32(STAT_A)
#undef STAT_A
    }
    __syncthreads();

    if (t < MM) {
        const float r  = fmaxf(sqrtf(s_part[0][t]), 1e-12f);
        s_c[t]  = s_b[t] - EPS * r;               // unnormalized feasibility threshold
        s_e2[t] = 1e-12f * r;                     // unnormalized slack clamp
        const float adw = s_part[1][t] / r;
        const float sw  = (s_b[t] - s_part[2][t]) / r;
        s_red[t] = (adw > 0.f) ? (sw / fmaxf(adw, 1e-12f)) : INFINITY;
    }
    __syncthreads();
    if (t < 64) s_red[t] = fminf(s_red[t], s_red[t + 64]);
    __syncthreads();
    if (t < 32) s_red[t] = fminf(s_red[t], s_red[t + 32]);
    __syncthreads();
    if (t < 16) s_red[t] = fminf(s_red[t], s_red[t + 16]);
    __syncthreads();
    if (t < 8)  s_red[t] = fminf(s_red[t], s_red[t + 8]);
    __syncthreads();
    if (t < 4)  s_red[t] = fminf(s_red[t], s_red[t + 4]);
    __syncthreads();
    if (t == 0) {
        const float v = fminf(fminf(s_red[0], s_red[1]), fminf(s_red[2], s_red[3]));
        s_t0 = fmaxf(0.5f * v, 2.0f * EPS);
    }
    __syncthreads();
    const float t0 = s_t0;

    s_x[t] = s_lower[t] + t0;
    if (t < MM) s_ax[t] = s_part[2][t] + t0 * s_part[1][t];
    __syncthreads();

    // ---- feasibility repair branch (faithful; no-op for these inputs) ----
    {
        int ok = (s_x[t] >= s_lower[t] + EPS);
        if (t < MM) ok = ok && (s_ax[t] <= s_c[t]);
        const int feas = __syncthreads_and(ok);
        if (!feas) {
            s_x[t] = 0.5f * (fmaxf(s_x[t], 0.f) + s_lower[t]);
            __syncthreads();
            const float4 x4 = ((const float4*)s_x)[lane];
#define REPAIR_A(i) { \
            float _px = a##i.x*x4.x + a##i.y*x4.y + a##i.z*x4.z + a##i.w*x4.w; \
            BFLY_ADD(_px); \
            if (lane == 0) s_ax[wave*32 + (i)] = _px; }
            REPEAT32(REPAIR_A)
#undef REPAIR_A
            __syncthreads();
        }
    }

    const float mystep = (lane < MAX_LS) ? ldexpf(1.0f, -lane) : 0.0f;

    for (int k = 0; k < K_ITER; ++k) {
        if (t < MM) s_w[t] = MU / fmaxf(s_b[t] - s_ax[t], s_e2[t]);
        if (t == 0) s_mask = 0xFFFFFFFFu;
        __syncthreads();

        // -- pass 1: column partials of A^T w (registers only) --
        float4 pp = make_float4(0.f, 0.f, 0.f, 0.f);
#define P1_A(i) { const float _wm = s_w[wave*32 + (i)]; \
        pp.x = fmaf(a##i.x, _wm, pp.x); pp.y = fmaf(a##i.y, _wm, pp.y); \
        pp.z = fmaf(a##i.z, _wm, pp.z); pp.w = fmaf(a##i.w, _wm, pp.w); }
        REPEAT32(P1_A)
#undef P1_A
        ((float4*)s_part[wave])[lane] = pp;
        __syncthreads();

        // -- gradient + n-side line-search mask (thread == column) --
        {
            const float g  = (s_part[0][t] + s_part[1][t]) + (s_part[2][t] + s_part[3][t]);
            const float xt = s_x[t];
            const float gr = (xt - s_xraw[t]) + g + MU / fmaxf(xt - s_lower[t], 1e-12f);
            s_grad[t] = gr;

            unsigned mn = 0u;
            const float loe = s_lower[t] + EPS;
            float st = 1.0f;
            #pragma unroll
            for (int l = 0; l < MAX_LS; ++l) {
                if (xt - st * gr >= loe) mn |= (1u << l);
                st *= 0.5f;
            }
            mn &= __shfl_xor(mn, 1);  mn &= __shfl_xor(mn, 2);
            mn &= __shfl_xor(mn, 4);  mn &= __shfl_xor(mn, 8);
            mn &= __shfl_xor(mn, 16); mn &= __shfl_xor(mn, 32);
            if (lane == 0) atomicAnd(&s_mask, mn);
        }
        __syncthreads();   // s_grad complete; s_part free

        // -- pass 2: Ag, fresh Ax from registers; m-side mask --
        {
            const float4 g4 = ((const float4*)s_grad)[lane];
            const float4 x4 = ((const float4*)s_x)[lane];
            unsigned mm = 0xFFFFFFFFu;
#define P2_A(i) { \
            float _pg = a##i.x*g4.x + a##i.y*g4.y + a##i.z*g4.z + a##i.w*g4.w; \
            float _px = a##i.x*x4.x + a##i.y*x4.y + a##i.z*x4.z + a##i.w*x4.w; \
            BFLY_ADD(_pg); BFLY_ADD(_px); \
            bool _okm = true; \
            if (lane < MAX_LS) _okm = (_px - mystep * _pg) <= s_c[wave*32 + (i)]; \
            const unsigned long long _bal = __ballot(_okm); \
            mm &= ((unsigned)_bal | ~FULLMASK); \
            if (lane == 0) { s_part[0][wave*32 + (i)] = _px; s_part[1][wave*32 + (i)] = _pg; } }
            REPEAT32(P2_A)
#undef P2_A
            if (lane == 0) atomicAnd(&s_mask, mm);
        }
        __syncthreads();

        // -- inline global AND-barrier (no calls => registers stay put) --
        if (t == 0) {
            atomicAnd(&gmask[k], s_mask & FULLMASK);
            __threadfence();
            const unsigned old = atomicAdd(&cnt[k], 1u);
            if (old == NPROB - 1) {
                __threadfence();
                const unsigned gm = __hip_atomic_load(&gmask[k], __ATOMIC_RELAXED,
                                                      __HIP_MEMORY_SCOPE_AGENT);
                const unsigned v = 0x80000000u | gm;
                __hip_atomic_store(&done[k], v, __ATOMIC_RELEASE,
                                   __HIP_MEMORY_SCOPE_AGENT);
                s_done = v;
            } else {
                unsigned v;
                do {
                    __builtin_amdgcn_s_sleep(1);
                    v = __hip_atomic_load(&done[k], __ATOMIC_ACQUIRE,
                                          __HIP_MEMORY_SCOPE_AGENT);
                } while (v == 0u);
                s_done = v;
            }
        }
        __syncthreads();

        const unsigned gm = s_done & FULLMASK;
        const float step = gm ? ldexpf(1.0f, -(__ffs(gm) - 1)) : 0.0f;
        s_x[t] -= step * s_grad[t];
        if (t < MM) s_ax[t] = s_part[0][t] - step * s_part[1][t];
        __syncthreads();
    }

    out_g[p*NN + t] = fmaxf(s_x[t], 0.0f);
}

// ================= fallback path (round-2 kernels, proven 851 us) =========
__global__ __launch_bounds__(1024, 8)
void lbp_init(const float* __restrict__ A_g,
              const float* __restrict__ b_g,
              const float* __restrict__ lower_g,
              float* __restrict__ ws,
              unsigned* __restrict__ gmask)
{
    const int p    = blockIdx.x;
    const int t    = threadIdx.x;
    const int lane = t & 63;
    const int wave = t >> 6;

    const float* A  = A_g + (size_t)p * (MM * NN);
    const float* bb = b_g + p * MM;

    __shared__ __align__(16) float s_lower[NN];
    __shared__ __align__(16) float s_x[NN];
    __shared__ float s_ssq[MM], s_rs[MM], s_al[MM];
    __shared__ float s_red[MM];
    __shared__ float s_t0;

    if (t < NN) s_lower[t] = lower_g[p * NN + t];
    __syncthreads();

    {
        const float4 lo4 = ((const float4*)s_lower)[lane];
        #pragma unroll 2
        for (int i = 0; i < 8; ++i) {
            const int m = wave * 8 + i;
            const float4 a4 = ((const float4*)(A + m * NN))[lane];
            float ssq = a4.x*a4.x + a4.y*a4.y + a4.z*a4.z + a4.w*a4.w;
            float rs  = a4.x + a4.y + a4.z + a4.w;
            float al  = a4.x*lo4.x + a4.y*lo4.y + a4.z*lo4.z + a4.w*lo4.w;
            BFLY_ADD(ssq); BFLY_ADD(rs); BFLY_ADD(al);
            if (lane == 0) { s_ssq[m] = ssq; s_rs[m] = rs; s_al[m] = al; }
        }
    }
    __syncthreads();

    if (t < MM) {
        const float r = fmaxf(sqrtf(s_ssq[t]), 1e-12f);
        s_ssq[t] = r;
        ws[OR_ + p * MM + t] = r;
        const float adw = s_rs[t] / r;
        const float sw  = (bb[t] - s_al[t]) / r;
        s_red[t] = (adw > 0.f) ? (sw / fmaxf(adw, 1e-12f)) : INFINITY;
    }
    __syncthreads();
    if (t < 64) s_red[t] = fminf(s_red[t], s_red[t + 64]);
    __syncthreads();
    if (t < 32) s_red[t] = fminf(s_red[t], s_red[t + 32]);
    __syncthreads();
    if (t < 16) s_red[t] = fminf(s_red[t], s_red[t + 16]);
    __syncthreads();
    if (t < 8)  s_red[t] = fminf(s_red[t], s_red[t + 8]);
    __syncthreads();
    if (t < 4)  s_red[t] = fminf(s_red[t], s_red[t + 4]);
    __syncthreads();
    if (t == 0) s_t0 = fmaxf(0.5f * fminf(fminf(s_red[0], s_red[1]),
                                          fminf(s_red[2], s_red[3])), 2.0f * EPS);
    __syncthreads();
    const float t0 = s_t0;

    float x = 0.f, ax = 0.f;
    if (t < NN) x  = s_lower[t] + t0;
    if (t < MM) ax = s_al[t] + t0 * s_rs[t];

    int ok = 1;
    if (t < MM) ok = ok && (ax <= bb[t] - EPS * s_ssq[t]);
    if (t < NN) ok = ok && (x >= s_lower[t] + EPS);
    const int feas = __syncthreads_and(ok);
    if (!feas) {
        if (t < NN) { x = 0.5f * (fmaxf(x, 0.f) + s_lower[t]); s_x[t] = x; }
        __syncthreads();
        const float4 x4 = ((const float4*)s_x)[lane];
        for (int i = 0; i < 8; ++i) {
            const int m = wave * 8 + i;
            const float4 a4 = ((const float4*)(A + m * NN))[lane];
            float px = a4.x*x4.x + a4.y*x4.y + a4.z*x4.z + a4.w*x4.w;
            BFLY_ADD(px);
            if (lane == 0) s_al[m] = px;
        }
        __syncthreads();
        if (t < MM) ax = s_al[t];
    }

    if (t < NN) ws[OX  + p * NN + t] = x;
    if (t < MM) ws[OAX + p * MM + t] = ax;
    if (p == 0 && t < K_ITER) gmask[t] = FULLMASK;
}

__global__ __launch_bounds__(1024, 8)
void lbp_iter(const float* __restrict__ A_g,
              const float* __restrict__ b_g,
              const float* __restrict__ xraw_g,
              const float* __restrict__ lower_g,
              float* __restrict__ ws,
              unsigned* __restrict__ gmask,
              int k)
{
    const int p    = blockIdx.x;
    const int t    = threadIdx.x;
    const int lane = t & 63;
    const int wave = t >> 6;

    const float* A  = A_g + (size_t)p * (MM * NN);
    const float* bb = b_g + p * MM;

    __shared__ __align__(16) float s_x[NN];
    __shared__ __align__(16) float s_grad[NN];
    __shared__ __align__(16) float s_xraw[NN];
    __shared__ __align__(16) float s_lower[NN];
    __shared__ float s_w[MM], s_c[MM];
    __shared__ float s_part[4][NN];
    __shared__ unsigned s_mask;

    if (t == 0) s_mask = 0xFFFFFFFFu;
    if (t < NN) { s_xraw[t] = xraw_g[p * NN + t]; s_lower[t] = lower_g[p * NN + t]; }

    float step = 0.f;
    if (k > 0) {
        const unsigned gm = gmask[k - 1];
        step = gm ? ldexpf(1.0f, -(__ffs(gm) - 1)) : 0.0f;
    }
    if (t < NN) {
        float x = ws[OX + p * NN + t];
        if (k > 0) { x -= step * ws[OG + p * NN + t]; ws[OX + p * NN + t] = x; }
        s_x[t] = x;
    }
    if (t < MM) {
        float ax = ws[OAX + p * MM + t];
        if (k > 0) ax -= step * ws[OAG + p * MM + t];
        const float r  = ws[OR_ + p * MM + t];
        const float bm = bb[t];
        s_c[t] = bm - EPS * r;
        s_w[t] = MU / fmaxf(bm - ax, 1e-12f * r);
    }
    __syncthreads();

    {
        const int col = t & (NN - 1);
        const int q   = t >> 8;
        const float* Ac = A + (size_t)(q * 32) * NN + col;
        float g = 0.f;
        #pragma unroll 8
        for (int j = 0; j < 32; ++j) g = fmaf(Ac[(size_t)j * NN], s_w[q * 32 + j], g);
        s_part[q][col] = g;
    }
    __syncthreads();

    if (t < NN) {
        const float g  = s_part[0][t] + s_part[1][t] + s_part[2][t] + s_part[3][t];
        const float xt = s_x[t];
        const float gr = (xt - s_xraw[t]) + g + MU / fmaxf(xt - s_lower[t], 1e-12f);
        s_grad[t] = gr;
        ws[OG + p * NN + t] = gr;

        unsigned mn = 0u;
        const float loe = s_lower[t] + EPS;
        float st = 1.0f;
        #pragma unroll
        for (int l = 0; l < MAX_LS; ++l) {
            if (xt - st * gr >= loe) mn |= (1u << l);
            st *= 0.5f;
        }
        mn &= __shfl_xor(mn, 1);  mn &= __shfl_xor(mn, 2);
        mn &= __shfl_xor(mn, 4);  mn &= __shfl_xor(mn, 8);
        mn &= __shfl_xor(mn, 16); mn &= __shfl_xor(mn, 32);
        if (lane == 0) atomicAnd(&s_mask, mn);
    }
    __syncthreads();

    {
        const float4 g4 = ((const float4*)s_grad)[lane];
        const float4 x4 = ((const float4*)s_x)[lane];
        const float mystep = (lane < MAX_LS) ? ldexpf(1.0f, -lane) : 0.0f;
        unsigned mm = 0xFFFFFFFFu;
        #pragma unroll 2
        for (int i = 0; i < 8; ++i) {
            const int m = wave * 8 + i;
            const float4 a4 = ((const float4*)(A + m * NN))[lane];
            float pg = a4.x*g4.x + a4.y*g4.y + a4.z*g4.z + a4.w*g4.w;
            float px = a4.x*x4.x + a4.y*x4.y + a4.z*x4.z + a4.w*x4.w;
            BFLY_ADD(pg); BFLY_ADD(px);
            bool okm = true;
            if (lane < MAX_LS) okm = (px - mystep * pg) <= s_c[m];
            const unsigned long long bal = __ballot(okm);
            mm &= ((unsigned)bal | ~FULLMASK);
            if (lane == 0) { ws[OAG + p * MM + m] = pg; ws[OAX + p * MM + m] = px; }
        }
        if (lane == 0) atomicAnd(&s_mask, mm);
    }
    __syncthreads();

    if (t == 0) atomicAnd(&gmask[k], s_mask & FULLMASK);
}

__global__ __launch_bounds__(256)
void lbp_fin(const float* __restrict__ ws,
             const unsigned* __restrict__ gmask,
             float* __restrict__ out_g)
{
    const int p = blockIdx.x;
    const int t = threadIdx.x;
    const unsigned gm = gmask[K_ITER - 1];
    const float step = gm ? ldexpf(1.0f, -(__ffs(gm) - 1)) : 0.0f;
    const float x = ws[OX + p * NN + t] - step * ws[OG + p * NN + t];
    out_g[p * NN + t] = fmaxf(x, 0.0f);
}

// -------------------------------------------------------------- launch ----
extern "C" void kernel_launch(void* const* d_in, const int* in_sizes, int n_in,
                              void* d_out, int out_size, void* d_ws, size_t ws_size,
                              hipStream_t stream) {
    const float* xraw  = (const float*)d_in[0];
    const float* A     = (const float*)d_in[1];
    const float* b     = (const float*)d_in[2];
    const float* lower = (const float*)d_in[3];
    float* out = (float*)d_out;

    unsigned* gmask = (unsigned*)d_ws;
    unsigned* cnt   = (unsigned*)((char*)d_ws + 128);
    unsigned* done  = (unsigned*)((char*)d_ws + 256);
    float* ws2 = (float*)((char*)d_ws + 1024);

    lbp_ctrl_init<<<1, 64, 0, stream>>>(gmask, cnt, done);

    void* args[] = { (void*)&xraw, (void*)&A, (void*)&b, (void*)&lower,
                     (void*)&out, (void*)&gmask, (void*)&cnt, (void*)&done };
    hipError_t err = hipLaunchCooperativeKernel((const void*)lbp_persist,
                                                dim3(NPROB), dim3(256),
                                                args, 0, stream);
    if (err != hipSuccess) {
        // deterministic fallback: proven multi-kernel path (~851 us)
        lbp_init<<<NPROB, 1024, 0, stream>>>(A, b, lower, ws2, gmask);
        for (int k = 0; k < K_ITER; ++k)
            lbp_iter<<<NPROB, 1024, 0, stream>>>(A, b, xraw, lower, ws2, gmask, k);
        lbp_fin<<<NPROB, 256, 0, stream>>>(ws2, gmask, out);
    }
}